// Round 11
// baseline (31805.161 us; speedup 1.0000x reference)
//
#include <hip/hip_runtime.h>
#include <hip/hip_bf16.h>

// mLSTM persistent v11: parity-tagged in-place exchange. Producer stores carry
// a step-parity bit in each bf16 LSB -> no drain, no flags, no polls; the
// consumer's validated burst-read IS the sync (one MALL round-trip per leg).
// L=512, N=32, H=1024, 2 layers. Out: ys | hs(2,32,1024) | cs(2,32,1024), fp32.

typedef unsigned short u16;
typedef unsigned int u32;
typedef unsigned long long u64;
typedef __attribute__((ext_vector_type(8))) short bf16x8;
typedef __attribute__((ext_vector_type(4))) float f32x4;

#define LSEQ 512
#define NB   32
#define HD   1024
#define G4   4096
#define YSZ  (LSEQ*NB*HD)
#define NH32 (NB*HD)
#define SEG  64
#define NSEG (LSEQ/SEG)
#define PERSIST_LDS 163840   // 128KB Wgm + 32KB Wmh

#define ATOMIC_RLX __ATOMIC_RELAXED
#define SCOPE_AGT __HIP_MEMORY_SCOPE_AGENT
#define PAR_MASK 0x0001000100010001ULL

__device__ __forceinline__ float b2f(u16 u) {
    u32 i = ((u32)u) << 16; float f; __builtin_memcpy(&f, &i, 4); return f;
}
__device__ __forceinline__ u16 f2b(float f) {
    u32 x; __builtin_memcpy(&x, &f, 4);
    return (u16)((x + 0x7fffu + ((x >> 16) & 1u)) >> 16);
}
__device__ __forceinline__ int SW(int row, int byte) { return byte ^ ((row & 7) << 4); }

// ---------------- init / conversion ----------------
__global__ void k_fill(u32* __restrict__ d, int n, u32 v) {
    int i = blockIdx.x * blockDim.x + threadIdx.x;
    if (i < n) d[i] = v;
}
__global__ void k_cvt(const float* __restrict__ s, u16* __restrict__ d, long n) {
    long i = (long)blockIdx.x * blockDim.x + threadIdx.x;
    long stride = (long)gridDim.x * blockDim.x;
    for (; i < n; i += stride) d[i] = f2b(s[i]);
}

template<typename XT> __device__ __forceinline__ bf16x8 ld8(const XT* p);
template<> __device__ __forceinline__ bf16x8 ld8<u16>(const u16* p) {
    return *(const bf16x8*)p;
}
template<> __device__ __forceinline__ bf16x8 ld8<float>(const float* p) {
    float4 a = *(const float4*)p, b = *(const float4*)(p + 4);
    bf16x8 r;
    r[0]=(short)f2b(a.x); r[1]=(short)f2b(a.y); r[2]=(short)f2b(a.z); r[3]=(short)f2b(a.w);
    r[4]=(short)f2b(b.x); r[5]=(short)f2b(b.y); r[6]=(short)f2b(b.z); r[7]=(short)f2b(b.w);
    return r;
}

// ------- big GEMM: Out[M][ldo] = bf16(X[M][1024] @ W[ncols][1024]^T + bias) -------
template<typename XT>
__global__ __launch_bounds__(256) void k_gemm(
    const XT* __restrict__ X, const u16* __restrict__ W,
    const float* __restrict__ bias, u16* __restrict__ Out, int ldo)
{
    __shared__ u16 As[128][40];
    __shared__ u16 Bs[128][40];
    int bm = blockIdx.y, bn = blockIdx.x;
    int tid = threadIdx.x;
    int w = tid >> 6, lane = tid & 63;
    int wm = w >> 1, wn = w & 1;
    int l16 = lane & 15, lk = lane >> 4;

    f32x4 acc[4][4];
    #pragma unroll
    for (int i = 0; i < 4; ++i)
        #pragma unroll
        for (int j = 0; j < 4; ++j) acc[i][j] = (f32x4){0.f, 0.f, 0.f, 0.f};

    for (int kt = 0; kt < 32; ++kt) {
        __syncthreads();
        #pragma unroll
        for (int c = 0; c < 2; ++c) {
            int cid = tid + c * 256;
            int rrow = cid >> 2, kc = (cid & 3) * 8;
            *(bf16x8*)(&As[rrow][kc]) = ld8<XT>(X + (long)(bm * 128 + rrow) * HD + kt * 32 + kc);
            *(bf16x8*)(&Bs[rrow][kc]) = ld8<u16>(W + (long)(bn * 128 + rrow) * HD + kt * 32 + kc);
        }
        __syncthreads();
        bf16x8 af[4], bfr[4];
        #pragma unroll
        for (int mt = 0; mt < 4; ++mt)
            af[mt] = *(const bf16x8*)(&As[wm * 64 + mt * 16 + l16][lk * 8]);
        #pragma unroll
        for (int nt = 0; nt < 4; ++nt)
            bfr[nt] = *(const bf16x8*)(&Bs[wn * 64 + nt * 16 + l16][lk * 8]);
        #pragma unroll
        for (int mt = 0; mt < 4; ++mt)
            #pragma unroll
            for (int nt = 0; nt < 4; ++nt)
                acc[mt][nt] = __builtin_amdgcn_mfma_f32_16x16x32_bf16(
                    af[mt], bfr[nt], acc[mt][nt], 0, 0, 0);
    }
    #pragma unroll
    for (int mt = 0; mt < 4; ++mt)
        #pragma unroll
        for (int nt = 0; nt < 4; ++nt) {
            int colg = bn * 128 + wn * 64 + nt * 16 + l16;
            float bv = bias[colg];
            #pragma unroll
            for (int r = 0; r < 4; ++r) {
                int rowg = bm * 128 + wm * 64 + mt * 16 + lk * 4 + r;
                Out[(long)rowg * ldo + colg] = f2b(acc[mt][nt][r] + bv);
            }
        }
}

// ---------------- persistent recurrent kernel (one 64-step segment) ----------------
// 64 blocks x 256 thr, 1 block/CU (160KB LDS). Block b owns h/m-cols [16b,16b+16).
// Waves 2,3: phase1 (m). Waves 0,1: phase2 (g/h/c). Parity-tagged exchange:
// h/m bf16 LSB = step parity; validated burst-read replaces drain+flag+poll.
__global__ __launch_bounds__(256, 1) void k_persist(
    const u16* __restrict__ Wmhb, const float* __restrict__ bmh,
    const u16* __restrict__ Wgmb,
    const u16* __restrict__ Ab,    // [512][32][1024] layer-local (tbi+t indexed)
    const u16* __restrict__ Gxb,   // [SEG][32][4096] segment-local
    u16* eh, u16* em,              // [32][1024] parity-tagged exchange
    float* __restrict__ cbuf,      // [32][1024] f32 c-state
    u16* __restrict__ yb, float* __restrict__ yf,
    float* __restrict__ tail,      // out + YSZ
    int l, int tbc, int tbi)
{
    extern __shared__ __align__(16) char lds[];
    const int tid = threadIdx.x;
    const int b = blockIdx.x;
    const int w = tid >> 6, lane = tid & 63;
    const int l16 = lane & 15, lk = lane >> 4;

    // ---- stage Wgm slice (4 gates x 16 cols = 128KB) + Wmh slice (16 cols = 32KB) ----
    for (int it = 0; it < 32; ++it) {
        int cch = tid + it * 256;
        int lr = cch >> 7, k8 = cch & 127;
        int g = lr >> 4, c16 = lr & 15;
        bf16x8 v = *(const bf16x8*)(Wgmb + (long)(g * 1024 + 16 * b + c16) * HD + k8 * 8);
        *(bf16x8*)(lds + SW(lr, lr * 2048 + k8 * 16)) = v;
    }
    for (int it = 0; it < 8; ++it) {
        int cch = tid + it * 256;
        int lr = cch >> 7, k8 = cch & 127;
        bf16x8 v = *(const bf16x8*)(Wmhb + (long)(16 * b + lr) * HD + k8 * 8);
        *(bf16x8*)(lds + 131072 + SW(lr, lr * 2048 + k8 * 16)) = v;
    }
    __syncthreads();   // only block-wide sync

    const int colg = 16 * b + l16;

    if (w >= 2) {
        // ================= phase 1: m = A_t * (h @ Wmh^T + bmh) =================
        const int rt = w - 2;
        const float bcol = bmh[colg];
        const u64* hrow = (const u64*)eh + (rt * 16 + l16) * (HD / 4);
        u16* mdst = em + (rt * 16 + lk * 4) * HD + colg;

        for (int t = 0; t < SEG; ++t) {
            const u32 gt = (u32)(tbc + t);
            const u64 exph = ((gt & 1u) == 0) ? PAR_MASK : 0ULL;  // h_{gt-1} parity
            const u16 pm = (u16)(gt & 1u);                        // m_gt parity
            const u16* At = Ab + (long)(tbi + t) * NH32;
            u16 atv[4];
            #pragma unroll
            for (int r = 0; r < 4; ++r)
                atv[r] = At[(rt * 16 + lk * 4 + r) * HD + colg];
            // ---- validated burst-read of h (sync + data in one round trip) ----
            u64 hq[64];
            for (;;) {
                #pragma unroll
                for (int kt = 0; kt < 32; ++kt) {
                    hq[2*kt]   = __hip_atomic_load(hrow + kt * 8 + lk * 2,     ATOMIC_RLX, SCOPE_AGT);
                    hq[2*kt+1] = __hip_atomic_load(hrow + kt * 8 + lk * 2 + 1, ATOMIC_RLX, SCOPE_AGT);
                }
                u64 d = 0;
                #pragma unroll
                for (int j = 0; j < 64; ++j) d |= (hq[j] ^ exph);
                if (__all((d & PAR_MASK) == 0)) break;
                __builtin_amdgcn_s_sleep(1);
            }
            __builtin_amdgcn_sched_barrier(0);
            f32x4 acc = (f32x4){0.f, 0.f, 0.f, 0.f};
            #pragma unroll
            for (int kt = 0; kt < 32; ++kt) {
                union { bf16x8 v; u64 q[2]; } u;
                u.q[0] = hq[2*kt]; u.q[1] = hq[2*kt+1];
                bf16x8 bfrag = *(const bf16x8*)(lds + 131072 +
                                SW(l16, l16 * 2048 + kt * 64 + lk * 16));
                acc = __builtin_amdgcn_mfma_f32_16x16x32_bf16(u.v, bfrag, acc, 0, 0, 0);
            }
            #pragma unroll
            for (int r = 0; r < 4; ++r) {
                u16 v = (u16)((f2b(b2f(atv[r]) * (acc[r] + bcol)) & 0xFFFEu) | pm);
                __hip_atomic_store(mdst + r * HD, v, ATOMIC_RLX, SCOPE_AGT);
            }
            // no drain, no flag — parity carries validity
        }
    } else {
        // ===== phase 2: g = Gx_t + m @ Wgm^T; gates; h,c (all 4 gates per lane) =====
        const int rt = w;
        f32x4 creg;
        #pragma unroll
        for (int r = 0; r < 4; ++r)
            creg[r] = cbuf[(rt * 16 + lk * 4 + r) * HD + colg];
        const u64* mrow = (const u64*)em + (rt * 16 + l16) * (HD / 4);

        for (int t = 0; t < SEG; ++t) {
            const u32 gt = (u32)(tbc + t);
            const u64 expm = (gt & 1u) ? PAR_MASK : 0ULL;   // m_gt parity
            const u16 pm = (u16)(gt & 1u);                  // h_gt parity
            const u16* Gx = Gxb + (long)t * NB * G4;
            u16 gxv[4][4];
            #pragma unroll
            for (int g = 0; g < 4; ++g)
                #pragma unroll
                for (int r = 0; r < 4; ++r)
                    gxv[g][r] = Gx[(long)(rt * 16 + lk * 4 + r) * G4 + g * 1024 + colg];
            // ---- validated burst-read of m ----
            u64 mq[64];
            for (;;) {
                #pragma unroll
                for (int kt = 0; kt < 32; ++kt) {
                    mq[2*kt]   = __hip_atomic_load(mrow + kt * 8 + lk * 2,     ATOMIC_RLX, SCOPE_AGT);
                    mq[2*kt+1] = __hip_atomic_load(mrow + kt * 8 + lk * 2 + 1, ATOMIC_RLX, SCOPE_AGT);
                }
                u64 d = 0;
                #pragma unroll
                for (int j = 0; j < 64; ++j) d |= (mq[j] ^ expm);
                if (__all((d & PAR_MASK) == 0)) break;
                __builtin_amdgcn_s_sleep(1);
            }
            __builtin_amdgcn_sched_barrier(0);
            f32x4 gacc[4];
            #pragma unroll
            for (int g = 0; g < 4; ++g) gacc[g] = (f32x4){0.f, 0.f, 0.f, 0.f};
            #pragma unroll
            for (int kt = 0; kt < 32; ++kt) {
                union { bf16x8 v; u64 q[2]; } u;
                u.q[0] = mq[2*kt]; u.q[1] = mq[2*kt+1];
                #pragma unroll
                for (int g = 0; g < 4; ++g) {
                    int lr = g * 16 + l16;
                    bf16x8 bfrag = *(const bf16x8*)(lds + SW(lr, lr * 2048 + kt * 64 + lk * 16));
                    gacc[g] = __builtin_amdgcn_mfma_f32_16x16x32_bf16(u.v, bfrag, gacc[g], 0, 0, 0);
                }
            }
            float hn[4];
            #pragma unroll
            for (int r = 0; r < 4; ++r) {
                int row = rt * 16 + lk * 4 + r;
                float ig = gacc[0][r] + b2f(gxv[0][r]);
                float fg = gacc[1][r] + b2f(gxv[1][r]);
                float zg = gacc[2][r] + b2f(gxv[2][r]);
                float og = gacc[3][r] + b2f(gxv[3][r]);
                float si = 1.f / (1.f + expf(-ig));
                float sf = 1.f / (1.f + expf(-fg));
                float so = 1.f / (1.f + expf(-og));
                float cn = sf * creg[r] + si * tanhf(zg);
                hn[r] = so * tanhf(cn);
                creg[r] = cn;
                u16 v = (u16)((f2b(hn[r]) & 0xFFFEu) | pm);
                __hip_atomic_store(eh + (long)row * HD + colg, v, ATOMIC_RLX, SCOPE_AGT);
            }
            // outputs (off the dependency chain; no drain needed)
            #pragma unroll
            for (int r = 0; r < 4; ++r) {
                int row = rt * 16 + lk * 4 + r;
                long yidx = (long)(tbi + t) * NH32 + (long)row * HD + colg;
                if (yb) yb[yidx] = f2b(hn[r]); else yf[yidx] = hn[r];
                if (tbi + t == LSEQ - 1) {
                    tail[(long)l * NH32 + row * HD + colg] = hn[r];
                    tail[2L * NH32 + (long)l * NH32 + row * HD + colg] = creg[r];
                }
            }
        }
        #pragma unroll
        for (int r = 0; r < 4; ++r)
            cbuf[(rt * 16 + lk * 4 + r) * HD + colg] = creg[r];
    }
}

extern "C" void kernel_launch(void* const* d_in, const int* in_sizes, int n_in,
                              void* d_out, int out_size, void* d_ws, size_t ws_size,
                              hipStream_t stream) {
    (void)in_sizes; (void)n_in; (void)out_size; (void)ws_size;
    const float* inputs = (const float*)d_in[0];
    const float* Wmx[2] = {(const float*)d_in[1], (const float*)d_in[8]};
    const float* Wmh[2] = {(const float*)d_in[2], (const float*)d_in[9]};
    const float* bmx[2] = {(const float*)d_in[3], (const float*)d_in[10]};
    const float* bmh[2] = {(const float*)d_in[4], (const float*)d_in[11]};
    const float* Wgx[2] = {(const float*)d_in[5], (const float*)d_in[12]};
    const float* Wgm[2] = {(const float*)d_in[6], (const float*)d_in[13]};
    const float* bg[2]  = {(const float*)d_in[7], (const float*)d_in[14]};
    float* out = (float*)d_out;

    char* ws = (char*)d_ws;
    const long MB = 1024L * 1024L;
    u16* Wmxb[2] = {(u16*)(ws + 0 * MB),  (u16*)(ws + 2 * MB)};
    u16* Wmhb[2] = {(u16*)(ws + 4 * MB),  (u16*)(ws + 6 * MB)};
    u16* Wgxb[2] = {(u16*)(ws + 8 * MB),  (u16*)(ws + 16 * MB)};
    u16* Wgmb[2] = {(u16*)(ws + 24 * MB), (u16*)(ws + 32 * MB)};
    u16* Yb  = (u16*)(ws + 40 * MB);   // 32MB bf16 layer-0 outputs
    u16* Ab  = (u16*)(ws + 72 * MB);   // 32MB bf16 A = x@Wmx+bmx (per layer)
    u16* Gxb = (u16*)(ws + 104 * MB);  // 16MB bf16 Gx chunk
    char* ex = ws + 120 * MB;
    u16* exch_h = (u16*)ex;                       // 64KB parity-tagged h
    u16* exch_m = (u16*)(ex + 65536);             // 64KB parity-tagged m
    float* cbuf = (float*)(ex + 131072);          // 128KB c-state

    hipFuncSetAttribute((const void*)k_persist,
                        hipFuncAttributeMaxDynamicSharedMemorySize, PERSIST_LDS);

    // init: h/m filled with parity-1 denormal words (h_{-1}=~0 valid; m invalid);
    // c zeroed. Re-run every call -> graph-replay deterministic.
    k_fill<<<128, 256, 0, stream>>>((u32*)ex, 32768, 0x00010001u);
    hipMemsetAsync(cbuf, 0, 131072, stream);

    k_cvt<<<512, 256, 0, stream>>>(Wmx[0], Wmxb[0], (long)HD * HD);
    k_cvt<<<512, 256, 0, stream>>>(Wmx[1], Wmxb[1], (long)HD * HD);
    k_cvt<<<512, 256, 0, stream>>>(Wmh[0], Wmhb[0], (long)HD * HD);
    k_cvt<<<512, 256, 0, stream>>>(Wmh[1], Wmhb[1], (long)HD * HD);
    k_cvt<<<1024, 256, 0, stream>>>(Wgx[0], Wgxb[0], (long)G4 * HD);
    k_cvt<<<1024, 256, 0, stream>>>(Wgx[1], Wgxb[1], (long)G4 * HD);
    k_cvt<<<1024, 256, 0, stream>>>(Wgm[0], Wgmb[0], (long)G4 * HD);
    k_cvt<<<1024, 256, 0, stream>>>(Wgm[1], Wgmb[1], (long)G4 * HD);

    for (int l = 0; l < 2; ++l) {
        if (l == 0)
            k_gemm<float><<<dim3(8, 128), 256, 0, stream>>>(inputs, Wmxb[0], bmx[0], Ab, HD);
        else
            k_gemm<u16><<<dim3(8, 128), 256, 0, stream>>>(Yb, Wmxb[1], bmx[1], Ab, HD);
        for (int s = 0; s < NSEG; ++s) {
            if (l == 0)
                k_gemm<float><<<dim3(32, 16), 256, 0, stream>>>(
                    inputs + (long)s * SEG * NB * HD, Wgxb[0], bg[0], Gxb, G4);
            else
                k_gemm<u16><<<dim3(32, 16), 256, 0, stream>>>(
                    Yb + (long)s * SEG * NB * HD, Wgxb[1], bg[1], Gxb, G4);
            k_persist<<<64, 256, PERSIST_LDS, stream>>>(
                Wmhb[l], bmh[l], Wgmb[l], Ab, Gxb,
                exch_h, exch_m, cbuf,
                l ? nullptr : Yb, l ? out : nullptr, out + YSZ,
                l, l * LSEQ + s * SEG, s * SEG);
        }
    }
}

// Round 12
// 16802.621 us; speedup vs baseline: 1.8929x; 1.8929x over previous
//
#include <hip/hip_runtime.h>
#include <hip/hip_bf16.h>

// mLSTM persistent v12: sentinel-gated parity exchange.
// Producers store parity-tagged bf16 (LSB = step parity): no drain, no flags.
// One wave polls 128 sentinel DATA words (v10 single-poller + barrier), then
// consumers do one validated burst read (retry ~never). Legs cost 2-3 RTs.
// L=512, N=32, H=1024, 2 layers. Out: ys | hs(2,32,1024) | cs(2,32,1024), fp32.

typedef unsigned short u16;
typedef unsigned int u32;
typedef unsigned long long u64;
typedef __attribute__((ext_vector_type(8))) short bf16x8;
typedef __attribute__((ext_vector_type(4))) float f32x4;

#define LSEQ 512
#define NB   32
#define HD   1024
#define G4   4096
#define YSZ  (LSEQ*NB*HD)
#define NH32 (NB*HD)
#define SEG  64
#define NSEG (LSEQ/SEG)
#define PERSIST_LDS 163840   // 128KB Wgm + 32KB Wmh

#define ATOMIC_RLX __ATOMIC_RELAXED
#define SCOPE_AGT __HIP_MEMORY_SCOPE_AGENT
#define PAR_MASK 0x0001000100010001ULL

__device__ __forceinline__ float b2f(u16 u) {
    u32 i = ((u32)u) << 16; float f; __builtin_memcpy(&f, &i, 4); return f;
}
__device__ __forceinline__ u16 f2b(float f) {
    u32 x; __builtin_memcpy(&x, &f, 4);
    return (u16)((x + 0x7fffu + ((x >> 16) & 1u)) >> 16);
}
__device__ __forceinline__ int SW(int row, int byte) { return byte ^ ((row & 7) << 4); }

// Poll the 128 sentinel data words (lane -> block, rows 3 and 19) until their
// parity LSB matches `par`. Sweep = 2 u16/lane -> v7-flag-sized poll traffic.
__device__ __forceinline__ void poll_sent(const u16* ebuf, u32 par) {
    const int lane = threadIdx.x & 63;
    const u16* p0 = ebuf + 3 * HD + 16 * lane;    // rt=0 producer-wave sentinel
    const u16* p1 = ebuf + 19 * HD + 16 * lane;   // rt=1 producer-wave sentinel
    for (;;) {
        u16 a = __hip_atomic_load(p0, ATOMIC_RLX, SCOPE_AGT);
        u16 b = __hip_atomic_load(p1, ATOMIC_RLX, SCOPE_AGT);
        if (__all((((a ^ par) & 1u) | ((b ^ par) & 1u)) == 0)) break;
        __builtin_amdgcn_s_sleep(1);
    }
    asm volatile("" ::: "memory");
}

// ---------------- init / conversion ----------------
__global__ void k_fill(u32* __restrict__ d, int n, u32 v) {
    int i = blockIdx.x * blockDim.x + threadIdx.x;
    if (i < n) d[i] = v;
}
__global__ void k_cvt(const float* __restrict__ s, u16* __restrict__ d, long n) {
    long i = (long)blockIdx.x * blockDim.x + threadIdx.x;
    long stride = (long)gridDim.x * blockDim.x;
    for (; i < n; i += stride) d[i] = f2b(s[i]);
}

template<typename XT> __device__ __forceinline__ bf16x8 ld8(const XT* p);
template<> __device__ __forceinline__ bf16x8 ld8<u16>(const u16* p) {
    return *(const bf16x8*)p;
}
template<> __device__ __forceinline__ bf16x8 ld8<float>(const float* p) {
    float4 a = *(const float4*)p, b = *(const float4*)(p + 4);
    bf16x8 r;
    r[0]=(short)f2b(a.x); r[1]=(short)f2b(a.y); r[2]=(short)f2b(a.z); r[3]=(short)f2b(a.w);
    r[4]=(short)f2b(b.x); r[5]=(short)f2b(b.y); r[6]=(short)f2b(b.z); r[7]=(short)f2b(b.w);
    return r;
}

// ------- big GEMM: Out[M][ldo] = bf16(X[M][1024] @ W[ncols][1024]^T + bias) -------
template<typename XT>
__global__ __launch_bounds__(256) void k_gemm(
    const XT* __restrict__ X, const u16* __restrict__ W,
    const float* __restrict__ bias, u16* __restrict__ Out, int ldo)
{
    __shared__ u16 As[128][40];
    __shared__ u16 Bs[128][40];
    int bm = blockIdx.y, bn = blockIdx.x;
    int tid = threadIdx.x;
    int w = tid >> 6, lane = tid & 63;
    int wm = w >> 1, wn = w & 1;
    int l16 = lane & 15, lk = lane >> 4;

    f32x4 acc[4][4];
    #pragma unroll
    for (int i = 0; i < 4; ++i)
        #pragma unroll
        for (int j = 0; j < 4; ++j) acc[i][j] = (f32x4){0.f, 0.f, 0.f, 0.f};

    for (int kt = 0; kt < 32; ++kt) {
        __syncthreads();
        #pragma unroll
        for (int c = 0; c < 2; ++c) {
            int cid = tid + c * 256;
            int rrow = cid >> 2, kc = (cid & 3) * 8;
            *(bf16x8*)(&As[rrow][kc]) = ld8<XT>(X + (long)(bm * 128 + rrow) * HD + kt * 32 + kc);
            *(bf16x8*)(&Bs[rrow][kc]) = ld8<u16>(W + (long)(bn * 128 + rrow) * HD + kt * 32 + kc);
        }
        __syncthreads();
        bf16x8 af[4], bfr[4];
        #pragma unroll
        for (int mt = 0; mt < 4; ++mt)
            af[mt] = *(const bf16x8*)(&As[wm * 64 + mt * 16 + l16][lk * 8]);
        #pragma unroll
        for (int nt = 0; nt < 4; ++nt)
            bfr[nt] = *(const bf16x8*)(&Bs[wn * 64 + nt * 16 + l16][lk * 8]);
        #pragma unroll
        for (int mt = 0; mt < 4; ++mt)
            #pragma unroll
            for (int nt = 0; nt < 4; ++nt)
                acc[mt][nt] = __builtin_amdgcn_mfma_f32_16x16x32_bf16(
                    af[mt], bfr[nt], acc[mt][nt], 0, 0, 0);
    }
    #pragma unroll
    for (int mt = 0; mt < 4; ++mt)
        #pragma unroll
        for (int nt = 0; nt < 4; ++nt) {
            int colg = bn * 128 + wn * 64 + nt * 16 + l16;
            float bv = bias[colg];
            #pragma unroll
            for (int r = 0; r < 4; ++r) {
                int rowg = bm * 128 + wm * 64 + mt * 16 + lk * 4 + r;
                Out[(long)rowg * ldo + colg] = f2b(acc[mt][nt][r] + bv);
            }
        }
}

// ---------------- persistent recurrent kernel (one 64-step segment) ----------------
// 64 blocks x 256 thr, 1 block/CU (160KB LDS). Block b owns h/m-cols [16b,16b+16).
// Waves 2,3: phase1 (m), rt=w-2... via rt=w&1. Waves 0,1: phase2 (g/h/c).
// Wave 2 polls h-sentinels, wave 0 polls m-sentinels; barriers broadcast.
__global__ __launch_bounds__(256, 1) void k_persist(
    const u16* __restrict__ Wmhb, const float* __restrict__ bmh,
    const u16* __restrict__ Wgmb,
    const u16* __restrict__ Ab,    // [512][32][1024] layer-local (tbi+t indexed)
    const u16* __restrict__ Gxb,   // [SEG][32][4096] segment-local
    u16* eh, u16* em,              // [32][1024] parity-tagged exchange
    float* __restrict__ cbuf,      // [32][1024] f32 c-state
    u16* __restrict__ yb, float* __restrict__ yf,
    float* __restrict__ tail,      // out + YSZ
    int l, int tbc, int tbi)
{
    extern __shared__ __align__(16) char lds[];
    const int tid = threadIdx.x;
    const int b = blockIdx.x;
    const int w = tid >> 6, lane = tid & 63;
    const int l16 = lane & 15, lk = lane >> 4;

    // ---- stage Wgm slice (4 gates x 16 cols = 128KB) + Wmh slice (16 cols = 32KB) ----
    for (int it = 0; it < 32; ++it) {
        int cch = tid + it * 256;
        int lr = cch >> 7, k8 = cch & 127;
        int g = lr >> 4, c16 = lr & 15;
        bf16x8 v = *(const bf16x8*)(Wgmb + (long)(g * 1024 + 16 * b + c16) * HD + k8 * 8);
        *(bf16x8*)(lds + SW(lr, lr * 2048 + k8 * 16)) = v;
    }
    for (int it = 0; it < 8; ++it) {
        int cch = tid + it * 256;
        int lr = cch >> 7, k8 = cch & 127;
        bf16x8 v = *(const bf16x8*)(Wmhb + (long)(16 * b + lr) * HD + k8 * 8);
        *(bf16x8*)(lds + 131072 + SW(lr, lr * 2048 + k8 * 16)) = v;
    }
    __syncthreads();

    const int colg = 16 * b + l16;
    const int rt = w & 1;                 // row-tile (waves {0,2}->rows 0-15, {1,3}->16-31)
    const bool isP1 = (w >= 2);

    const float bcol = bmh[colg];
    const u64* hrow = (const u64*)eh + (rt * 16 + l16) * (HD / 4);   // P1 consumer
    u16* mdst = em + (rt * 16 + lk * 4) * HD + colg;                 // P1 producer
    const u64* mrow = (const u64*)em + (rt * 16 + l16) * (HD / 4);   // P2 consumer
    f32x4 creg = (f32x4){0.f, 0.f, 0.f, 0.f};
    if (!isP1)
        #pragma unroll
        for (int r = 0; r < 4; ++r)
            creg[r] = cbuf[(rt * 16 + lk * 4 + r) * HD + colg];

    for (int t = 0; t < SEG; ++t) {
        const u32 gt = (u32)(tbc + t);
        const u32 hp = (gt + 1) & 1u;     // parity of h_{t-1}
        const u32 mp = gt & 1u;           // parity of m_t and h_t
        const u64 exph = hp ? PAR_MASK : 0ULL;
        const u64 expm = mp ? PAR_MASK : 0ULL;
        // ---- dependency-free prefetches ----
        u16 atv[4];
        u16 gxv[4][4];
        if (isP1) {
            const u16* At = Ab + (long)(tbi + t) * NH32;
            #pragma unroll
            for (int r = 0; r < 4; ++r)
                atv[r] = At[(rt * 16 + lk * 4 + r) * HD + colg];
        } else {
            const u16* Gx = Gxb + (long)t * NB * G4;
            #pragma unroll
            for (int g = 0; g < 4; ++g)
                #pragma unroll
                for (int r = 0; r < 4; ++r)
                    gxv[g][r] = Gx[(long)(rt * 16 + lk * 4 + r) * G4 + g * 1024 + colg];
        }
        // ---- gate: h_{t-1} sentinels (only wave 2 polls; barrier broadcasts) ----
        if (w == 2) poll_sent(eh, hp);
        __syncthreads();
        // ---- phase 1: m = A_t * (h @ Wmh^T + bmh) ----
        if (isP1) {
            u64 hq[64];
            for (;;) {
                #pragma unroll
                for (int kt = 0; kt < 32; ++kt) {
                    hq[2*kt]   = __hip_atomic_load(hrow + kt * 8 + lk * 2,     ATOMIC_RLX, SCOPE_AGT);
                    hq[2*kt+1] = __hip_atomic_load(hrow + kt * 8 + lk * 2 + 1, ATOMIC_RLX, SCOPE_AGT);
                }
                u64 d = 0;
                #pragma unroll
                for (int j = 0; j < 64; ++j) d |= (hq[j] ^ exph);
                if (__all((d & PAR_MASK) == 0)) break;
                __builtin_amdgcn_s_sleep(1);
            }
            __builtin_amdgcn_sched_barrier(0);
            f32x4 acc = (f32x4){0.f, 0.f, 0.f, 0.f};
            #pragma unroll
            for (int kt = 0; kt < 32; ++kt) {
                union { bf16x8 v; u64 q[2]; } u;
                u.q[0] = hq[2*kt]; u.q[1] = hq[2*kt+1];
                bf16x8 bfrag = *(const bf16x8*)(lds + 131072 +
                                SW(l16, l16 * 2048 + kt * 64 + lk * 16));
                acc = __builtin_amdgcn_mfma_f32_16x16x32_bf16(u.v, bfrag, acc, 0, 0, 0);
            }
            #pragma unroll
            for (int r = 0; r < 4; ++r) {
                u16 v = (u16)((f2b(b2f(atv[r]) * (acc[r] + bcol)) & 0xFFFEu) | (u16)mp);
                __hip_atomic_store(mdst + r * HD, v, ATOMIC_RLX, SCOPE_AGT);
            }
            // no drain, no flag — sentinel word above is part of the data
        }
        // ---- gate: m_t sentinels (only wave 0 polls; barrier broadcasts) ----
        if (w == 0) poll_sent(em, mp);
        __syncthreads();
        // ---- phase 2: g = Gx_t + m @ Wgm^T; gates; h,c ----
        if (!isP1) {
            u64 mq[64];
            for (;;) {
                #pragma unroll
                for (int kt = 0; kt < 32; ++kt) {
                    mq[2*kt]   = __hip_atomic_load(mrow + kt * 8 + lk * 2,     ATOMIC_RLX, SCOPE_AGT);
                    mq[2*kt+1] = __hip_atomic_load(mrow + kt * 8 + lk * 2 + 1, ATOMIC_RLX, SCOPE_AGT);
                }
                u64 d = 0;
                #pragma unroll
                for (int j = 0; j < 64; ++j) d |= (mq[j] ^ expm);
                if (__all((d & PAR_MASK) == 0)) break;
                __builtin_amdgcn_s_sleep(1);
            }
            __builtin_amdgcn_sched_barrier(0);
            f32x4 gacc[4];
            #pragma unroll
            for (int g = 0; g < 4; ++g) gacc[g] = (f32x4){0.f, 0.f, 0.f, 0.f};
            #pragma unroll
            for (int kt = 0; kt < 32; ++kt) {
                union { bf16x8 v; u64 q[2]; } u;
                u.q[0] = mq[2*kt]; u.q[1] = mq[2*kt+1];
                #pragma unroll
                for (int g = 0; g < 4; ++g) {
                    int lr = g * 16 + l16;
                    bf16x8 bfrag = *(const bf16x8*)(lds + SW(lr, lr * 2048 + kt * 64 + lk * 16));
                    gacc[g] = __builtin_amdgcn_mfma_f32_16x16x32_bf16(u.v, bfrag, gacc[g], 0, 0, 0);
                }
            }
            float hn[4];
            #pragma unroll
            for (int r = 0; r < 4; ++r) {
                int row = rt * 16 + lk * 4 + r;
                float ig = gacc[0][r] + b2f(gxv[0][r]);
                float fg = gacc[1][r] + b2f(gxv[1][r]);
                float zg = gacc[2][r] + b2f(gxv[2][r]);
                float og = gacc[3][r] + b2f(gxv[3][r]);
                float si = 1.f / (1.f + expf(-ig));
                float sf = 1.f / (1.f + expf(-fg));
                float so = 1.f / (1.f + expf(-og));
                float cn = sf * creg[r] + si * tanhf(zg);
                hn[r] = so * tanhf(cn);
                creg[r] = cn;
                u16 v = (u16)((f2b(hn[r]) & 0xFFFEu) | (u16)mp);
                __hip_atomic_store(eh + (long)row * HD + colg, v, ATOMIC_RLX, SCOPE_AGT);
            }
            // outputs off the dependency chain (after h stores issued)
            #pragma unroll
            for (int r = 0; r < 4; ++r) {
                int row = rt * 16 + lk * 4 + r;
                long yidx = (long)(tbi + t) * NH32 + (long)row * HD + colg;
                if (yb) yb[yidx] = f2b(hn[r]); else yf[yidx] = hn[r];
                if (tbi + t == LSEQ - 1) {
                    tail[(long)l * NH32 + row * HD + colg] = hn[r];
                    tail[2L * NH32 + (long)l * NH32 + row * HD + colg] = creg[r];
                }
            }
        }
    }
    if (!isP1)
        #pragma unroll
        for (int r = 0; r < 4; ++r)
            cbuf[(rt * 16 + lk * 4 + r) * HD + colg] = creg[r];
}

extern "C" void kernel_launch(void* const* d_in, const int* in_sizes, int n_in,
                              void* d_out, int out_size, void* d_ws, size_t ws_size,
                              hipStream_t stream) {
    (void)in_sizes; (void)n_in; (void)out_size; (void)ws_size;
    const float* inputs = (const float*)d_in[0];
    const float* Wmx[2] = {(const float*)d_in[1], (const float*)d_in[8]};
    const float* Wmh[2] = {(const float*)d_in[2], (const float*)d_in[9]};
    const float* bmx[2] = {(const float*)d_in[3], (const float*)d_in[10]};
    const float* bmh[2] = {(const float*)d_in[4], (const float*)d_in[11]};
    const float* Wgx[2] = {(const float*)d_in[5], (const float*)d_in[12]};
    const float* Wgm[2] = {(const float*)d_in[6], (const float*)d_in[13]};
    const float* bg[2]  = {(const float*)d_in[7], (const float*)d_in[14]};
    float* out = (float*)d_out;

    char* ws = (char*)d_ws;
    const long MB = 1024L * 1024L;
    u16* Wmxb[2] = {(u16*)(ws + 0 * MB),  (u16*)(ws + 2 * MB)};
    u16* Wmhb[2] = {(u16*)(ws + 4 * MB),  (u16*)(ws + 6 * MB)};
    u16* Wgxb[2] = {(u16*)(ws + 8 * MB),  (u16*)(ws + 16 * MB)};
    u16* Wgmb[2] = {(u16*)(ws + 24 * MB), (u16*)(ws + 32 * MB)};
    u16* Yb  = (u16*)(ws + 40 * MB);   // 32MB bf16 layer-0 outputs
    u16* Ab  = (u16*)(ws + 72 * MB);   // 32MB bf16 A = x@Wmx+bmx (per layer)
    u16* Gxb = (u16*)(ws + 104 * MB);  // 16MB bf16 Gx chunk
    char* ex = ws + 120 * MB;
    u16* exch_h = (u16*)ex;                       // 64KB parity-tagged h
    u16* exch_m = (u16*)(ex + 65536);             // 64KB parity-tagged m
    float* cbuf = (float*)(ex + 131072);          // 128KB c-state

    hipFuncSetAttribute((const void*)k_persist,
                        hipFuncAttributeMaxDynamicSharedMemorySize, PERSIST_LDS);

    // init: h/m filled with parity-1 denormal words (h_{-1}=~0 valid at gt=0;
    // m invalid); c zeroed. Re-run every call -> graph-replay deterministic.
    k_fill<<<128, 256, 0, stream>>>((u32*)ex, 32768, 0x00010001u);
    hipMemsetAsync(cbuf, 0, 131072, stream);

    k_cvt<<<512, 256, 0, stream>>>(Wmx[0], Wmxb[0], (long)HD * HD);
    k_cvt<<<512, 256, 0, stream>>>(Wmx[1], Wmxb[1], (long)HD * HD);
    k_cvt<<<512, 256, 0, stream>>>(Wmh[0], Wmhb[0], (long)HD * HD);
    k_cvt<<<512, 256, 0, stream>>>(Wmh[1], Wmhb[1], (long)HD * HD);
    k_cvt<<<1024, 256, 0, stream>>>(Wgx[0], Wgxb[0], (long)G4 * HD);
    k_cvt<<<1024, 256, 0, stream>>>(Wgx[1], Wgxb[1], (long)G4 * HD);
    k_cvt<<<1024, 256, 0, stream>>>(Wgm[0], Wgmb[0], (long)G4 * HD);
    k_cvt<<<1024, 256, 0, stream>>>(Wgm[1], Wgmb[1], (long)G4 * HD);

    for (int l = 0; l < 2; ++l) {
        if (l == 0)
            k_gemm<float><<<dim3(8, 128), 256, 0, stream>>>(inputs, Wmxb[0], bmx[0], Ab, HD);
        else
            k_gemm<u16><<<dim3(8, 128), 256, 0, stream>>>(Yb, Wmxb[1], bmx[1], Ab, HD);
        for (int s = 0; s < NSEG; ++s) {
            if (l == 0)
                k_gemm<float><<<dim3(32, 16), 256, 0, stream>>>(
                    inputs + (long)s * SEG * NB * HD, Wgxb[0], bg[0], Gxb, G4);
            else
                k_gemm<u16><<<dim3(32, 16), 256, 0, stream>>>(
                    Yb + (long)s * SEG * NB * HD, Wgxb[1], bg[1], Gxb, G4);
            k_persist<<<64, 256, PERSIST_LDS, stream>>>(
                Wmhb[l], bmh[l], Wgmb[l], Ab, Gxb,
                exch_h, exch_m, cbuf,
                l ? nullptr : Yb, l ? out : nullptr, out + YSZ,
                l, l * LSEQ + s * SEG, s * SEG);
        }
    }
}

// Round 13
// 13923.459 us; speedup vs baseline: 2.2843x; 1.2068x over previous
//
#include <hip/hip_runtime.h>
#include <hip/hip_bf16.h>

// mLSTM persistent v13: v10 sync skeleton + wide coalesced exchange.
// Consumers: 16B sc0/sc1 loads (sector-merged). Producers: shuffle-transposed
// single-u64 atomic stores. Flags/drains/polls identical to v10 (proven).
// L=512, N=32, H=1024, 2 layers. Out: ys | hs(2,32,1024) | cs(2,32,1024), fp32.

typedef unsigned short u16;
typedef unsigned int u32;
typedef unsigned long long u64;
typedef __attribute__((ext_vector_type(8))) short bf16x8;
typedef __attribute__((ext_vector_type(4))) float f32x4;
typedef __attribute__((ext_vector_type(4))) unsigned int u32x4;

#define LSEQ 512
#define NB   32
#define HD   1024
#define G4   4096
#define YSZ  (LSEQ*NB*HD)
#define NH32 (NB*HD)
#define SEG  64
#define NSEG (LSEQ/SEG)
#define PERSIST_LDS 163840   // 128KB Wgm + 32KB Wmh

#define ATOMIC_RLX __ATOMIC_RELAXED
#define SCOPE_AGT __HIP_MEMORY_SCOPE_AGENT

__device__ __forceinline__ float b2f(u16 u) {
    u32 i = ((u32)u) << 16; float f; __builtin_memcpy(&f, &i, 4); return f;
}
__device__ __forceinline__ u16 f2b(float f) {
    u32 x; __builtin_memcpy(&x, &f, 4);
    return (u16)((x + 0x7fffu + ((x >> 16) & 1u)) >> 16);
}
__device__ __forceinline__ int SW(int row, int byte) { return byte ^ ((row & 7) << 4); }

// v10-proven poll: lane b gathers block b's 8B slot-pair; paced with s_sleep.
__device__ __forceinline__ void pollwait(const u32* flags, u32 target) {
    const int lane = threadIdx.x & 63;
    const u64* p = (const u64*)flags + (size_t)lane * 16;
    for (;;) {
        u64 v = __hip_atomic_load(p, ATOMIC_RLX, SCOPE_AGT);
        u32 lo = (u32)v, hi = (u32)(v >> 32);
        if (__all(lo >= target && hi >= target)) break;
        __builtin_amdgcn_s_sleep(4);
    }
    asm volatile("" ::: "memory");
}

// Consumer: 32x 16B coherence-point loads (sector-coalescing, unlike atomics).
// base = per-lane byte address; loads at base + kt*64. Fence per guide rule #18.
__device__ __forceinline__ void load_row16(const char* base, u32x4* dst) {
#pragma unroll
    for (int kt = 0; kt < 32; ++kt) {
        u64 a = (u64)(base + kt * 64);
        asm volatile("global_load_dwordx4 %0, %1, off sc0 sc1"
                     : "=v"(dst[kt]) : "v"(a));
    }
    asm volatile("s_waitcnt vmcnt(0)" ::: "memory");
    __builtin_amdgcn_sched_barrier(0);
}

// Producer: transpose 4 per-lane row-values (rows lk*4+r, col l16) across the
// wave so each lane stores ONE contiguous u64 (row rl, 4 cols) — 8x fewer,
// 4x wider store requests than 4 scattered u16 atomics.
__device__ __forceinline__ void store_transposed(u16* ebuf, int rowbase, int colbase,
                                                 const u16 mu[4]) {
    const int lane = threadIdx.x & 63;
    u32 wlo = (u32)mu[0] | ((u32)mu[1] << 16);
    u32 whi = (u32)mu[2] | ((u32)mu[3] << 16);
    const int rl = lane >> 2;            // local row 0..15 this lane will store
    const int r = rl & 3, lks = rl >> 2;
    u64 outv = 0;
#pragma unroll
    for (int i = 0; i < 4; ++i) {
        int s = lks * 16 + (lane & 3) * 4 + i;   // source lane (col-local, row-group)
        u32 a  = (u32)__shfl((int)wlo, s);
        u32 bb = (u32)__shfl((int)whi, s);
        u32 pick = (r & 2) ? bb : a;
        u32 val = (r & 1) ? (pick >> 16) : (pick & 0xFFFFu);
        outv |= (u64)val << (16 * i);
    }
    u64* dst = (u64*)(ebuf + (size_t)(rowbase + rl) * HD + colbase + (lane & 3) * 4);
    __hip_atomic_store(dst, outv, ATOMIC_RLX, SCOPE_AGT);
}

// ---------------- f32 -> bf16 conversion ----------------
__global__ void k_cvt(const float* __restrict__ s, u16* __restrict__ d, long n) {
    long i = (long)blockIdx.x * blockDim.x + threadIdx.x;
    long stride = (long)gridDim.x * blockDim.x;
    for (; i < n; i += stride) d[i] = f2b(s[i]);
}

template<typename XT> __device__ __forceinline__ bf16x8 ld8(const XT* p);
template<> __device__ __forceinline__ bf16x8 ld8<u16>(const u16* p) {
    return *(const bf16x8*)p;
}
template<> __device__ __forceinline__ bf16x8 ld8<float>(const float* p) {
    float4 a = *(const float4*)p, b = *(const float4*)(p + 4);
    bf16x8 r;
    r[0]=(short)f2b(a.x); r[1]=(short)f2b(a.y); r[2]=(short)f2b(a.z); r[3]=(short)f2b(a.w);
    r[4]=(short)f2b(b.x); r[5]=(short)f2b(b.y); r[6]=(short)f2b(b.z); r[7]=(short)f2b(b.w);
    return r;
}

// ------- big GEMM: Out[M][ldo] = bf16(X[M][1024] @ W[ncols][1024]^T + bias) -------
template<typename XT>
__global__ __launch_bounds__(256) void k_gemm(
    const XT* __restrict__ X, const u16* __restrict__ W,
    const float* __restrict__ bias, u16* __restrict__ Out, int ldo)
{
    __shared__ u16 As[128][40];
    __shared__ u16 Bs[128][40];
    int bm = blockIdx.y, bn = blockIdx.x;
    int tid = threadIdx.x;
    int w = tid >> 6, lane = tid & 63;
    int wm = w >> 1, wn = w & 1;
    int l16 = lane & 15, lk = lane >> 4;

    f32x4 acc[4][4];
    #pragma unroll
    for (int i = 0; i < 4; ++i)
        #pragma unroll
        for (int j = 0; j < 4; ++j) acc[i][j] = (f32x4){0.f, 0.f, 0.f, 0.f};

    for (int kt = 0; kt < 32; ++kt) {
        __syncthreads();
        #pragma unroll
        for (int c = 0; c < 2; ++c) {
            int cid = tid + c * 256;
            int rrow = cid >> 2, kc = (cid & 3) * 8;
            *(bf16x8*)(&As[rrow][kc]) = ld8<XT>(X + (long)(bm * 128 + rrow) * HD + kt * 32 + kc);
            *(bf16x8*)(&Bs[rrow][kc]) = ld8<u16>(W + (long)(bn * 128 + rrow) * HD + kt * 32 + kc);
        }
        __syncthreads();
        bf16x8 af[4], bfr[4];
        #pragma unroll
        for (int mt = 0; mt < 4; ++mt)
            af[mt] = *(const bf16x8*)(&As[wm * 64 + mt * 16 + l16][lk * 8]);
        #pragma unroll
        for (int nt = 0; nt < 4; ++nt)
            bfr[nt] = *(const bf16x8*)(&Bs[wn * 64 + nt * 16 + l16][lk * 8]);
        #pragma unroll
        for (int mt = 0; mt < 4; ++mt)
            #pragma unroll
            for (int nt = 0; nt < 4; ++nt)
                acc[mt][nt] = __builtin_amdgcn_mfma_f32_16x16x32_bf16(
                    af[mt], bfr[nt], acc[mt][nt], 0, 0, 0);
    }
    #pragma unroll
    for (int mt = 0; mt < 4; ++mt)
        #pragma unroll
        for (int nt = 0; nt < 4; ++nt) {
            int colg = bn * 128 + wn * 64 + nt * 16 + l16;
            float bv = bias[colg];
            #pragma unroll
            for (int r = 0; r < 4; ++r) {
                int rowg = bm * 128 + wm * 64 + mt * 16 + lk * 4 + r;
                Out[(long)rowg * ldo + colg] = f2b(acc[mt][nt][r] + bv);
            }
        }
}

// ---------------- persistent recurrent kernel (one 64-step segment) ----------------
// 64 blocks x 256 thr, 1 block/CU (160KB LDS). Block b owns h/m-cols [16b,16b+16).
// Uniform loop, 2 barriers/step. Waves 2,3: phase1 (m). Waves 0,1: phase2 (g/h/c).
__global__ __launch_bounds__(256, 1) void k_persist(
    const u16* __restrict__ Wmhb, const float* __restrict__ bmh,
    const u16* __restrict__ Wgmb,
    const u16* __restrict__ Ab,    // [512][32][1024] layer-local (tbi+t indexed)
    const u16* __restrict__ Gxb,   // [SEG][32][4096] segment-local
    u16* eh, u16* em,              // [32][1024] bf16 coherent exchange
    float* __restrict__ cbuf,      // [32][1024] f32 c-state
    u16* __restrict__ yb, float* __restrict__ yf,
    float* __restrict__ tail,      // out + YSZ
    int l, int tbc, int tbi, u32* fM, u32* fH)
{
    extern __shared__ __align__(16) char lds[];
    const int tid = threadIdx.x;
    const int b = blockIdx.x;
    const int w = tid >> 6, lane = tid & 63;
    const int l16 = lane & 15, lk = lane >> 4;

    // ---- stage Wgm slice (4 gates x 16 cols = 128KB) + Wmh slice (16 cols = 32KB) ----
    for (int it = 0; it < 32; ++it) {
        int cch = tid + it * 256;
        int lr = cch >> 7, k8 = cch & 127;
        int g = lr >> 4, c16 = lr & 15;
        bf16x8 v = *(const bf16x8*)(Wgmb + (long)(g * 1024 + 16 * b + c16) * HD + k8 * 8);
        *(bf16x8*)(lds + SW(lr, lr * 2048 + k8 * 16)) = v;
    }
    for (int it = 0; it < 8; ++it) {
        int cch = tid + it * 256;
        int lr = cch >> 7, k8 = cch & 127;
        bf16x8 v = *(const bf16x8*)(Wmhb + (long)(16 * b + lr) * HD + k8 * 8);
        *(bf16x8*)(lds + 131072 + SW(lr, lr * 2048 + k8 * 16)) = v;
    }
    __syncthreads();

    const int colg = 16 * b + l16;
    const int rt = w & 1;                 // row-tile (waves {0,2}->rows 0-15, {1,3}->16-31)
    const bool isP1 = (w >= 2);

    const float bcol = bmh[colg];
    const char* hbase = (const char*)eh + (size_t)(rt * 16 + l16) * 2048 + lk * 16;
    const char* mbase = (const char*)em + (size_t)(rt * 16 + l16) * 2048 + lk * 16;
    f32x4 creg = (f32x4){0.f, 0.f, 0.f, 0.f};
    if (!isP1)
        #pragma unroll
        for (int r = 0; r < 4; ++r)
            creg[r] = cbuf[(rt * 16 + lk * 4 + r) * HD + colg];

    for (int t = 0; t < SEG; ++t) {
        const u32 gt = (u32)(tbc + t);
        // ---- dependency-free prefetches ----
        u16 atv[4];
        u16 gxv[4][4];
        if (isP1) {
            const u16* At = Ab + (long)(tbi + t) * NH32;
            #pragma unroll
            for (int r = 0; r < 4; ++r)
                atv[r] = At[(rt * 16 + lk * 4 + r) * HD + colg];
        } else {
            const u16* Gx = Gxb + (long)t * NB * G4;
            #pragma unroll
            for (int g = 0; g < 4; ++g)
                #pragma unroll
                for (int r = 0; r < 4; ++r)
                    gxv[g][r] = Gx[(long)(rt * 16 + lk * 4 + r) * G4 + g * 1024 + colg];
        }
        // ---- wait: h_{t-1} ready (only wave 2 polls; barrier broadcasts) ----
        if (w == 2) pollwait(fH, gt);
        __syncthreads();
        // ---- phase 1: m = A_t * (h @ Wmh^T + bmh) ----
        if (isP1) {
            u32x4 hv[32];
            load_row16(hbase, hv);
            f32x4 acc = (f32x4){0.f, 0.f, 0.f, 0.f};
            #pragma unroll
            for (int kt = 0; kt < 32; ++kt) {
                union { u32x4 q; bf16x8 v; } u;
                u.q = hv[kt];
                bf16x8 bfrag = *(const bf16x8*)(lds + 131072 +
                                SW(l16, l16 * 2048 + kt * 64 + lk * 16));
                acc = __builtin_amdgcn_mfma_f32_16x16x32_bf16(u.v, bfrag, acc, 0, 0, 0);
            }
            u16 mu[4];
            #pragma unroll
            for (int r = 0; r < 4; ++r)
                mu[r] = f2b(b2f(atv[r]) * (acc[r] + bcol));
            store_transposed(em, rt * 16, 16 * b, mu);
            asm volatile("s_waitcnt vmcnt(0)" ::: "memory");
            if (lane == 0)
                __hip_atomic_store(fM + b * 32 + rt, gt + 1, ATOMIC_RLX, SCOPE_AGT);
        }
        // ---- wait: m_t ready (only wave 0 polls; barrier broadcasts) ----
        if (w == 0) pollwait(fM, gt + 1);
        __syncthreads();
        // ---- phase 2: g = Gx_t + m @ Wgm^T; gates; h,c ----
        if (!isP1) {
            u32x4 mv[32];
            load_row16(mbase, mv);
            f32x4 gacc[4];
            #pragma unroll
            for (int g = 0; g < 4; ++g) gacc[g] = (f32x4){0.f, 0.f, 0.f, 0.f};
            #pragma unroll
            for (int kt = 0; kt < 32; ++kt) {
                union { u32x4 q; bf16x8 v; } u;
                u.q = mv[kt];
                #pragma unroll
                for (int g = 0; g < 4; ++g) {
                    int lr = g * 16 + l16;
                    bf16x8 bfrag = *(const bf16x8*)(lds + SW(lr, lr * 2048 + kt * 64 + lk * 16));
                    gacc[g] = __builtin_amdgcn_mfma_f32_16x16x32_bf16(u.v, bfrag, gacc[g], 0, 0, 0);
                }
            }
            float hn[4];
            u16 hu[4];
            #pragma unroll
            for (int r = 0; r < 4; ++r) {
                float ig = gacc[0][r] + b2f(gxv[0][r]);
                float fg = gacc[1][r] + b2f(gxv[1][r]);
                float zg = gacc[2][r] + b2f(gxv[2][r]);
                float og = gacc[3][r] + b2f(gxv[3][r]);
                float si = 1.f / (1.f + expf(-ig));
                float sf = 1.f / (1.f + expf(-fg));
                float so = 1.f / (1.f + expf(-og));
                float cn = sf * creg[r] + si * tanhf(zg);
                hn[r] = so * tanhf(cn);
                creg[r] = cn;
                hu[r] = f2b(hn[r]);
            }
            store_transposed(eh, rt * 16, 16 * b, hu);
            asm volatile("s_waitcnt vmcnt(0)" ::: "memory");
            if (lane == 0)
                __hip_atomic_store(fH + b * 32 + rt, gt + 1, ATOMIC_RLX, SCOPE_AGT);
            // ---- outputs off the critical path ----
            #pragma unroll
            for (int r = 0; r < 4; ++r) {
                int row = rt * 16 + lk * 4 + r;
                long yidx = (long)(tbi + t) * NH32 + (long)row * HD + colg;
                if (yb) yb[yidx] = f2b(hn[r]); else yf[yidx] = hn[r];
                if (tbi + t == LSEQ - 1) {
                    tail[(long)l * NH32 + row * HD + colg] = hn[r];
                    tail[2L * NH32 + (long)l * NH32 + row * HD + colg] = creg[r];
                }
            }
        }
    }
    if (!isP1)
        #pragma unroll
        for (int r = 0; r < 4; ++r)
            cbuf[(rt * 16 + lk * 4 + r) * HD + colg] = creg[r];
}

extern "C" void kernel_launch(void* const* d_in, const int* in_sizes, int n_in,
                              void* d_out, int out_size, void* d_ws, size_t ws_size,
                              hipStream_t stream) {
    (void)in_sizes; (void)n_in; (void)out_size; (void)ws_size;
    const float* inputs = (const float*)d_in[0];
    const float* Wmx[2] = {(const float*)d_in[1], (const float*)d_in[8]};
    const float* Wmh[2] = {(const float*)d_in[2], (const float*)d_in[9]};
    const float* bmx[2] = {(const float*)d_in[3], (const float*)d_in[10]};
    const float* bmh[2] = {(const float*)d_in[4], (const float*)d_in[11]};
    const float* Wgx[2] = {(const float*)d_in[5], (const float*)d_in[12]};
    const float* Wgm[2] = {(const float*)d_in[6], (const float*)d_in[13]};
    const float* bg[2]  = {(const float*)d_in[7], (const float*)d_in[14]};
    float* out = (float*)d_out;

    char* ws = (char*)d_ws;
    const long MB = 1024L * 1024L;
    u16* Wmxb[2] = {(u16*)(ws + 0 * MB),  (u16*)(ws + 2 * MB)};
    u16* Wmhb[2] = {(u16*)(ws + 4 * MB),  (u16*)(ws + 6 * MB)};
    u16* Wgxb[2] = {(u16*)(ws + 8 * MB),  (u16*)(ws + 16 * MB)};
    u16* Wgmb[2] = {(u16*)(ws + 24 * MB), (u16*)(ws + 32 * MB)};
    u16* Yb  = (u16*)(ws + 40 * MB);   // 32MB bf16 layer-0 outputs
    u16* Ab  = (u16*)(ws + 72 * MB);   // 32MB bf16 A = x@Wmx+bmx (per layer)
    u16* Gxb = (u16*)(ws + 104 * MB);  // 16MB bf16 Gx chunk
    char* ex = ws + 120 * MB;
    u16* exch_h = (u16*)ex;                       // 64KB
    u16* exch_m = (u16*)(ex + 65536);             // 64KB
    float* cbuf = (float*)(ex + 131072);          // 128KB
    u32* fM     = (u32*)(ex + 262144);            // 64 x 128B slot lines
    u32* fH     = (u32*)(ex + 262144 + 8192);     // 64 x 128B slot lines

    hipFuncSetAttribute((const void*)k_persist,
                        hipFuncAttributeMaxDynamicSharedMemorySize, PERSIST_LDS);

    // zero exchange + c + flags each call (graph-replay deterministic)
    hipMemsetAsync(ex, 0, 262144 + 16384, stream);

    k_cvt<<<512, 256, 0, stream>>>(Wmx[0], Wmxb[0], (long)HD * HD);
    k_cvt<<<512, 256, 0, stream>>>(Wmx[1], Wmxb[1], (long)HD * HD);
    k_cvt<<<512, 256, 0, stream>>>(Wmh[0], Wmhb[0], (long)HD * HD);
    k_cvt<<<512, 256, 0, stream>>>(Wmh[1], Wmhb[1], (long)HD * HD);
    k_cvt<<<1024, 256, 0, stream>>>(Wgx[0], Wgxb[0], (long)G4 * HD);
    k_cvt<<<1024, 256, 0, stream>>>(Wgx[1], Wgxb[1], (long)G4 * HD);
    k_cvt<<<1024, 256, 0, stream>>>(Wgm[0], Wgmb[0], (long)G4 * HD);
    k_cvt<<<1024, 256, 0, stream>>>(Wgm[1], Wgmb[1], (long)G4 * HD);

    for (int l = 0; l < 2; ++l) {
        if (l == 0)
            k_gemm<float><<<dim3(8, 128), 256, 0, stream>>>(inputs, Wmxb[0], bmx[0], Ab, HD);
        else
            k_gemm<u16><<<dim3(8, 128), 256, 0, stream>>>(Yb, Wmxb[1], bmx[1], Ab, HD);
        for (int s = 0; s < NSEG; ++s) {
            if (l == 0)
                k_gemm<float><<<dim3(32, 16), 256, 0, stream>>>(
                    inputs + (long)s * SEG * NB * HD, Wgxb[0], bg[0], Gxb, G4);
            else
                k_gemm<u16><<<dim3(32, 16), 256, 0, stream>>>(
                    Yb + (long)s * SEG * NB * HD, Wgxb[1], bg[1], Gxb, G4);
            k_persist<<<64, 256, PERSIST_LDS, stream>>>(
                Wmhb[l], bmh[l], Wgmb[l], Ab, Gxb,
                exch_h, exch_m, cbuf,
                l ? nullptr : Yb, l ? out : nullptr, out + YSZ,
                l, l * LSEQ + s * SEG, s * SEG, fM, fH);
        }
    }
}